// Round 7
// baseline (223.832 us; speedup 1.0000x reference)
//
#include <hip/hip_runtime.h>
#include <hip/hip_bf16.h>

// InfoNCE loss, N=8192 D=512 C=128.
// Fixed-shift softmax (M=10): t_ij = s_ij/tau - 10 in [-20, 0].
//   Z_i  = sum_{class!=} e^{t_ij}
//   term = -t_p + log(Z + e^{t_p}) ~= -t_p + logZ + e^{t_p}/Z
// K2: brick = 128 rows x 512 cols (4 tiles of 128x128), 544 bricks = single
// dispatch round at 3 blocks/CU. Continuous 64-unit ring-3 pipeline (BK=32)
// across tile boundaries (never drains), counted vmcnt(4), XOR-swizzled LDS
// (0 conflicts, r5-verified), setprio on MFMA, XCD-chunked brick order.
// Row-side partials accumulate in LDS across tiles (1 store/brick, slot=sj);
// col-side partials stored per tile split by wave (slot=(wm,bi)), barrier-free.
// Coverage: ordered pair (i,j): b_i<b_j via row-side of brick(b_i,strip(j));
// b_i>b_j via col-side of brick(b_j,strip(i)); b_i==b_j via diag tile row-side.

constexpr int   D      = 512;
constexpr int   BT     = 128;        // tile dim
constexpr int   BK     = 32;         // k per unit
constexpr float TAUINV = 10.0f;
constexpr float SHIFT  = 10.0f;

typedef __attribute__((ext_vector_type(8))) short bf16x8;
typedef __attribute__((ext_vector_type(4))) float f32x4;

__device__ inline ushort f2bf(float x) {
    unsigned u = __builtin_bit_cast(unsigned, x);
    unsigned r = (u + 0x7fffu + ((u >> 16) & 1u)) >> 16;   // RNE
    return (ushort)r;
}

__device__ inline void gload_lds16(const ushort* g, ushort* l) {
    __builtin_amdgcn_global_load_lds(
        (const __attribute__((address_space(1))) void*)g,
        (__attribute__((address_space(3))) void*)l, 16, 0, 0);
}

// ---------------- K1: L2-normalize rows, f32 -> bf16 (+hist in block 0) ----
__global__ void k_normalize(const float* __restrict__ emb,
                            const int* __restrict__ classes,
                            ushort* __restrict__ normed,
                            int* __restrict__ hist, int n) {
    if (blockIdx.x == 0) {                    // class histogram, LDS-only
        __shared__ int h[128];
        if (threadIdx.x < 128) h[threadIdx.x] = 0;
        __syncthreads();
        for (int i = threadIdx.x; i < n; i += 256)
            atomicAdd(&h[classes[i] & 127], 1);
        __syncthreads();
        if (threadIdx.x < 128) hist[threadIdx.x] = h[threadIdx.x];
    }
    int row  = blockIdx.x * 4 + (threadIdx.x >> 6);
    int lane = threadIdx.x & 63;
    if (row >= n) return;
    const float4* src = (const float4*)(emb + (size_t)row * D);
    float4 a = src[lane * 2];
    float4 b = src[lane * 2 + 1];
    float ss = a.x*a.x + a.y*a.y + a.z*a.z + a.w*a.w
             + b.x*b.x + b.y*b.y + b.z*b.z + b.w*b.w;
#pragma unroll
    for (int m = 1; m < 64; m <<= 1) ss += __shfl_xor(ss, m, 64);
    float sc = 1.0f / fmaxf(sqrtf(ss), 1e-12f);
    uint4 o;
    o.x = (unsigned)f2bf(a.x * sc) | ((unsigned)f2bf(a.y * sc) << 16);
    o.y = (unsigned)f2bf(a.z * sc) | ((unsigned)f2bf(a.w * sc) << 16);
    o.z = (unsigned)f2bf(b.x * sc) | ((unsigned)f2bf(b.y * sc) << 16);
    o.w = (unsigned)f2bf(b.z * sc) | ((unsigned)f2bf(b.w * sc) << 16);
    *(uint4*)&normed[(size_t)row * D + lane * 8] = o;
}

// ---------------- K2: brick GEMM (128 x 512), continuous ring pipeline -----
// Rrow: [3][16][n] slot sj ; Rcol: [3][2][64][n] slot (wm, bi)
__global__ __launch_bounds__(256, 3) void k_zgemm(
    const ushort* __restrict__ normed, const int* __restrict__ classes,
    float* __restrict__ Rrow, float* __restrict__ Rcol, int n, int nbricks) {
    __shared__ ushort ring[3][2][BT * BK];    // 48 KB
    __shared__ float  redr[2][BT][3];         // 3 KB, row-side accumulator
    __shared__ int    clsc[512];              // 2 KB, strip column classes

    const int tid  = threadIdx.x;
    const int lane = tid & 63;
    const int w    = tid >> 6;
    const int wm   = w >> 1, wn = w & 1;
    const int l15  = lane & 15, l4 = lane >> 4;

    // XCD-chunked bijective swizzle (544 = 8 * 68)
    const int per = nbricks >> 3;
    int orig = (blockIdx.x & 7) * per + (blockIdx.x >> 3);

    // decode brick (bi, sj): bi4-groups of 4 rows x (16-bi4) strips
    int idx = orig, bi4 = 0;
    for (;;) { int c = 4 * (16 - bi4); if (idx < c) break; idx -= c; ++bi4; }
    const int span = 16 - bi4;
    const int bi = bi4 * 4 + idx / span;
    const int sj = bi4 + idx % span;
    const int row0 = bi * BT;
    const int c00  = sj * 512;

    // prologue staging of classes (before ring stages; drained at prologue wait)
    for (int t = tid; t < 512; t += 256) clsc[t] = classes[c00 + t];
    {   float* rf = &redr[0][0][0];
        for (int t = tid; t < 2 * BT * 3; t += 256) rf[t] = 0.f; }
    int crow[16];
#pragma unroll
    for (int t = 0; t < 16; ++t)
        crow[t] = classes[row0 + wm * 64 + (t >> 2) * 16 + l4 * 4 + (t & 3)];

    // ring staging addresses: chunk = 16 rows x 64B; wave w owns chunks 2w,2w+1
    // swizzle s(r) = (r>>1)&3 -> source slot cg = (l&3) ^ ((l>>3)&3)
    const int lrow = lane >> 2;
    const int cg   = (lane & 3) ^ ((lane >> 3) & 3);
    size_t gA[2], gB[2]; int lo[2];
#pragma unroll
    for (int it = 0; it < 2; ++it) {
        int chunk = w * 2 + it;
        int row   = chunk * 16 + lrow;
        gA[it] = (size_t)(row0 + row) * D + cg * 8;
        gB[it] = (size_t)(c00  + row) * D + cg * 8;
        lo[it] = chunk * 1024;                // byte offset in 8KB tile
    }
    char* ringb = (char*)&ring[0][0][0];

    auto STAGE = [&](int sbo, int ct2, int kk) {   // kk in shorts
        size_t boff = (size_t)(ct2 * 128) * D + kk;
#pragma unroll
        for (int it = 0; it < 2; ++it) {
            gload_lds16(normed + gA[it] + kk,   (ushort*)(ringb + sbo + lo[it]));
            gload_lds16(normed + gB[it] + boff, (ushort*)(ringb + sbo + 8192 + lo[it]));
        }
    };

    // prologue: units 0,1 in flight; wait unit 0 (4 newest = unit 1's loads)
    STAGE(0, 0, 0);
    STAGE(16384, 0, BK);
    __builtin_amdgcn_sched_barrier(0);
    asm volatile("s_waitcnt vmcnt(4) lgkmcnt(0)" ::: "memory");
    __builtin_amdgcn_s_barrier();
    __builtin_amdgcn_sched_barrier(0);

    int cbo = 0, sbo = 32768;                 // ring byte offsets (x16384)
    const size_t PC = (size_t)128 * n;        // Rcol plane stride
    const size_t PR = (size_t)16 * n;         // Rrow plane stride

    for (int ct = 0; ct < 4; ++ct) {
        f32x4 acc[4][4];
#pragma unroll
        for (int a = 0; a < 4; ++a)
#pragma unroll
            for (int b = 0; b < 4; ++b) acc[a][b] = (f32x4){0.f, 0.f, 0.f, 0.f};

#pragma unroll
        for (int kt = 0; kt < 16; ++kt) {
            const int v2 = ct * 16 + kt + 2;
            if (v2 < 64) STAGE(sbo, v2 >> 4, (v2 & 15) * BK);
            const char* la = ringb + cbo;
            const char* lb = ringb + cbo + 8192;
            bf16x8 af[4], bfr[4];
#pragma unroll
            for (int mf = 0; mf < 4; ++mf) {
                int ra = wm * 64 + mf * 16 + l15;
                af[mf] = *(const bf16x8*)(la + ra * 64 + ((l4 ^ ((ra >> 1) & 3)) << 4));
            }
#pragma unroll
            for (int nf = 0; nf < 4; ++nf) {
                int rb = wn * 64 + nf * 16 + l15;
                bfr[nf] = *(const bf16x8*)(lb + rb * 64 + ((l4 ^ ((rb >> 1) & 3)) << 4));
            }
            __builtin_amdgcn_s_setprio(1);
#pragma unroll
            for (int mf = 0; mf < 4; ++mf)
#pragma unroll
                for (int nf = 0; nf < 4; ++nf)
                    acc[mf][nf] = __builtin_amdgcn_mfma_f32_16x16x32_bf16(
                        af[mf], bfr[nf], acc[mf][nf], 0, 0, 0);
            __builtin_amdgcn_s_setprio(0);
            __builtin_amdgcn_sched_barrier(0);
            if (v2 < 64)       asm volatile("s_waitcnt vmcnt(4)" ::: "memory");
            else if (v2 == 64) asm volatile("s_waitcnt vmcnt(0)" ::: "memory");
            __builtin_amdgcn_s_barrier();
            __builtin_amdgcn_sched_barrier(0);
            cbo = (cbo == 32768) ? 0 : cbo + 16384;
            sbo = (sbo == 32768) ? 0 : sbo + 16384;
        }

        // ---- per-tile epilogue (barrier-free) ----
        const int bj = sj * 4 + ct;
        if (bj >= bi) {
            const int c0t = c00 + ct * 128;
            int ccv[4];
#pragma unroll
            for (int nf = 0; nf < 4; ++nf)
                ccv[nf] = clsc[ct * 128 + wn * 64 + nf * 16 + l15];
            float cq[4][3];
#pragma unroll
            for (int nf = 0; nf < 4; ++nf)
                cq[nf][0] = cq[nf][1] = cq[nf][2] = 0.f;
#pragma unroll
            for (int mf = 0; mf < 4; ++mf) {
#pragma unroll
                for (int r = 0; r < 4; ++r) {
                    const int rr = wm * 64 + mf * 16 + l4 * 4 + r;
                    const int rg = row0 + rr;
                    const int cr = crow[mf * 4 + r];
                    float z = 0.f, ns = 0.f, p1 = 0.f;
#pragma unroll
                    for (int nf = 0; nf < 4; ++nf) {
                        const int cc = wn * 64 + nf * 16 + l15;
                        float t = fmaf(acc[mf][nf][r], TAUINV, -SHIFT);
                        float e = __expf(t);
                        bool same = (cr == ccv[nf]);
                        bool dg   = (rg == c0t + cc);
                        if (!same) { z += e; cq[nf][0] += e; }
                        else if (!dg) {
                            ns += t; p1 += e; cq[nf][1] += t; cq[nf][2] += e;
                        }
                    }
#pragma unroll
                    for (int m = 1; m < 16; m <<= 1) {
                        z  += __shfl_xor(z,  m, 16);
                        ns += __shfl_xor(ns, m, 16);
                        p1 += __shfl_xor(p1, m, 16);
                    }
                    if (l15 == 0) {
                        redr[wn][rr][0] += z;
                        redr[wn][rr][1] += ns;
                        redr[wn][rr][2] += p1;
                    }
                }
            }
            if (bj > bi) {                    // col-side, slot (wm, bi)
#pragma unroll
                for (int nf = 0; nf < 4; ++nf) {
                    float a0 = cq[nf][0], a1 = cq[nf][1], a2 = cq[nf][2];
                    a0 += __shfl_xor(a0, 16, 64); a0 += __shfl_xor(a0, 32, 64);
                    a1 += __shfl_xor(a1, 16, 64); a1 += __shfl_xor(a1, 32, 64);
                    a2 += __shfl_xor(a2, 16, 64); a2 += __shfl_xor(a2, 32, 64);
                    if (l4 == 0) {
                        size_t o = ((size_t)wm * 64 + bi) * n
                                 + c0t + wn * 64 + nf * 16 + l15;
                        Rcol[o] = a0; Rcol[PC + o] = a1; Rcol[2 * PC + o] = a2;
                    }
                }
            }
        }
    }

    __syncthreads();                          // redr visible (drains stores too)
    if (tid < BT) {
        size_t o = (size_t)sj * n + row0 + tid;
        Rrow[o]          = redr[0][tid][0] + redr[1][tid][0];
        Rrow[PR + o]     = redr[0][tid][1] + redr[1][tid][1];
        Rrow[2 * PR + o] = redr[0][tid][2] + redr[1][tid][2];
    }
}

// ---------------- K3: per-row closed-form terms ----------------
__global__ void k_rowterms(const float* __restrict__ Rrow,
                           const float* __restrict__ Rcol,
                           const int* __restrict__ classes,
                           const int* __restrict__ hist,
                           float* __restrict__ rowloss,
                           float* __restrict__ rowcnt, int n) {
    int i = blockIdx.x * 256 + threadIdx.x;
    if (i >= n) return;
    const int b_i = i >> 7;
    const int s0  = b_i >> 2;
    const size_t PR = (size_t)16 * n;
    const size_t PC = (size_t)128 * n;
    float z = 0.f, ns = 0.f, p1 = 0.f;
    for (int sjj = s0; sjj < 16; ++sjj) {
        size_t o = (size_t)sjj * n + i;
        z += Rrow[o]; ns += Rrow[PR + o]; p1 += Rrow[2 * PR + o];
    }
    for (int s = 0; s < 2; ++s)
        for (int b = 0; b < b_i; ++b) {
            size_t o = ((size_t)s * 64 + b) * n + i;
            z += Rcol[o]; ns += Rcol[PC + o]; p1 += Rcol[2 * PC + o];
        }
    float c = (float)(hist[classes[i] & 127] - 1);
    rowloss[i] = -ns + c * logf(z) + p1 / z;
    rowcnt[i]  = c;
}

// ---------------- K4: final deterministic reduction ----------------
__global__ void k_final(const float* __restrict__ rowloss,
                        const float* __restrict__ rowcnt,
                        float* __restrict__ out, int n) {
    __shared__ float sl[1024];
    __shared__ float sc[1024];
    float l = 0.f, c = 0.f;
    for (int i = threadIdx.x; i < n; i += 1024) {
        l += rowloss[i];
        c += rowcnt[i];
    }
    sl[threadIdx.x] = l;
    sc[threadIdx.x] = c;
    __syncthreads();
    for (int s = 512; s > 0; s >>= 1) {
        if (threadIdx.x < s) {
            sl[threadIdx.x] += sl[threadIdx.x + s];
            sc[threadIdx.x] += sc[threadIdx.x + s];
        }
        __syncthreads();
    }
    if (threadIdx.x == 0)
        out[0] = (sc[0] > 0.f) ? sl[0] / sc[0] : 0.f;
}

extern "C" void kernel_launch(void* const* d_in, const int* in_sizes, int n_in,
                              void* d_out, int out_size, void* d_ws, size_t ws_size,
                              hipStream_t stream) {
    const float* emb     = (const float*)d_in[0];
    const int*   classes = (const int*)d_in[1];
    float*       out     = (float*)d_out;
    const int n = in_sizes[1];                 // 8192
    const int nbricks = 544;                   // sum_{g=0..15} 4*(16-g)

    ushort* normed  = (ushort*)d_ws;                                   // 8 MB
    float*  Rrow    = (float*)((char*)d_ws + (size_t)n * D * 2);       // 1.5 MB
    float*  Rcol    = Rrow + (size_t)3 * 16 * n;                       // 12.6 MB
    float*  rowloss = Rcol + (size_t)3 * 128 * n;
    float*  rowcnt  = rowloss + n;
    int*    hist    = (int*)(rowcnt + n);                              // 512 B

    k_normalize<<<n / 4, 256, 0, stream>>>(emb, classes, normed, hist, n);
    k_zgemm<<<nbricks, 256, 0, stream>>>(normed, classes, Rrow, Rcol, n, nbricks);
    k_rowterms<<<(n + 255) / 256, 256, 0, stream>>>(Rrow, Rcol, classes, hist, rowloss, rowcnt, n);
    k_final<<<1, 1024, 0, stream>>>(rowloss, rowcnt, out, n);
}

// Round 8
// 120.626 us; speedup vs baseline: 1.8556x; 1.8556x over previous
//
#include <hip/hip_runtime.h>
#include <hip/hip_bf16.h>

// InfoNCE loss, N=8192 D=512 C=128.
// Fixed-shift softmax (M=10): t_ij = s_ij/tau - 10 in [-20, 0].
//   Z_i  = sum_{class!=} e^{t_ij}
//   term = -t_p + log(Z + e^{t_p}) ~= -t_p + logZ + e^{t_p}/Z
// K2 = m97 structure (NO inline asm - compiler schedules waitcnts; r7 lesson:
// stores inside a counted-vmcnt loop poison the count): 128^2 tile, BK=64,
// single-buffered 32KB LDS, 2 __syncthreads/K-step, global_load_lds(16B),
// XOR-swizzled LDS reads (slot ^ ((r>>1)&7), 2-way = free). Symmetric
// coverage: 2080 upper-tri tiles in strips of 2 -> 1040 balanced blocks
// (~4/CU queued, 3 resident = m97 TLP regime). Row partials accumulate in
// LDS across the strip (slot = block ordinal in row, <=33); col partials
// buffered in LDS, flushed at block END only (wm-reduced, 64 slots).

constexpr int   D      = 512;
constexpr int   BT     = 128;
constexpr int   BK     = 64;
constexpr int   KST    = D / BK;     // 8
constexpr float TAUINV = 10.0f;
constexpr float SHIFT  = 10.0f;

typedef __attribute__((ext_vector_type(8))) short bf16x8;
typedef __attribute__((ext_vector_type(4))) float f32x4;

__device__ inline ushort f2bf(float x) {
    unsigned u = __builtin_bit_cast(unsigned, x);
    unsigned r = (u + 0x7fffu + ((u >> 16) & 1u)) >> 16;   // RNE
    return (ushort)r;
}

__device__ inline void gload_lds16(const ushort* g, ushort* l) {
    __builtin_amdgcn_global_load_lds(
        (const __attribute__((address_space(1))) void*)g,
        (__attribute__((address_space(3))) void*)l, 16, 0, 0);
}

// ---------------- K1: L2-normalize rows, f32 -> bf16 (+hist in block 0) ----
__global__ void k_normalize(const float* __restrict__ emb,
                            const int* __restrict__ classes,
                            ushort* __restrict__ normed,
                            int* __restrict__ hist, int n) {
    if (blockIdx.x == 0) {
        __shared__ int h[128];
        if (threadIdx.x < 128) h[threadIdx.x] = 0;
        __syncthreads();
        for (int i = threadIdx.x; i < n; i += 256)
            atomicAdd(&h[classes[i] & 127], 1);
        __syncthreads();
        if (threadIdx.x < 128) hist[threadIdx.x] = h[threadIdx.x];
    }
    int row  = blockIdx.x * 4 + (threadIdx.x >> 6);
    int lane = threadIdx.x & 63;
    if (row >= n) return;
    const float4* src = (const float4*)(emb + (size_t)row * D);
    float4 a = src[lane * 2];
    float4 b = src[lane * 2 + 1];
    float ss = a.x*a.x + a.y*a.y + a.z*a.z + a.w*a.w
             + b.x*b.x + b.y*b.y + b.z*b.z + b.w*b.w;
#pragma unroll
    for (int m = 1; m < 64; m <<= 1) ss += __shfl_xor(ss, m, 64);
    float sc = 1.0f / fmaxf(sqrtf(ss), 1e-12f);
    uint4 o;
    o.x = (unsigned)f2bf(a.x * sc) | ((unsigned)f2bf(a.y * sc) << 16);
    o.y = (unsigned)f2bf(a.z * sc) | ((unsigned)f2bf(a.w * sc) << 16);
    o.z = (unsigned)f2bf(b.x * sc) | ((unsigned)f2bf(b.y * sc) << 16);
    o.w = (unsigned)f2bf(b.z * sc) | ((unsigned)f2bf(b.w * sc) << 16);
    *(uint4*)&normed[(size_t)row * D + lane * 8] = o;
}

// ---------------- K2: symmetric masked-exp GEMM, m97 structure -------------
// Rrow: [3][33][n] (slot = blk ordinal in row); Rcol: [3][64][n] (slot = bi).
__global__ __launch_bounds__(256, 3) void k_zgemm(
    const ushort* __restrict__ normed, const int* __restrict__ classes,
    float* __restrict__ Rrow, float* __restrict__ Rcol, int n) {
    __shared__ char  sbuf[32768];             // A 16KB | B 16KB, single buffer
    __shared__ float redr[2][BT][3];          // row partials (accum over strip)
    __shared__ float redc[2][2][BT][3];       // col partials [wm][tl][cc][q]
    __shared__ int   clsc[BT];

    const int tid = threadIdx.x, lane = tid & 63, w = tid >> 6;
    const int wm = w >> 1, wn = w & 1, l15 = lane & 15, l4 = lane >> 4;
    const size_t QR = (size_t)33 * n;
    const size_t QC = (size_t)64 * n;

    // XCD-chunked order (1040 = 8 * 130): consecutive orig per XCD
    const int per  = gridDim.x >> 3;
    const int orig = (blockIdx.x & 7) * per + (blockIdx.x >> 3);

    // staging constants: row r0 = tid>>3, slot = tid&7, swizzled source slot
    const int r0 = tid >> 3;
    const int srcslot = (tid & 7) ^ ((r0 >> 1) & 7);

    { float* f = &redr[0][0][0]; for (int u = tid; u < 2*BT*3; u += 256) f[u] = 0.f; }

    int curbi = -1, curbase = 0;
    int cbi[2], cc0[2]; bool cval[2];
    int crow[16];

#pragma unroll
    for (int tl = 0; tl < 2; ++tl) {
        const int p = orig * 2 + tl;
        int bi = 0, base = 0;
        while (base + (64 - bi) <= p) { base += 64 - bi; ++bi; }
        const int bj = bi + (p - base);
        if (bi != curbi) {
            if (curbi >= 0) {                  // flush finished row's partials
                __syncthreads();
                if (tid < BT) {
                    int slot = orig - (curbase >> 1);
                    size_t o = (size_t)slot * n + curbi * BT + tid;
                    Rrow[o]          = redr[0][tid][0] + redr[1][tid][0];
                    Rrow[QR + o]     = redr[0][tid][1] + redr[1][tid][1];
                    Rrow[2 * QR + o] = redr[0][tid][2] + redr[1][tid][2];
                }
                __syncthreads();
                float* f = &redr[0][0][0];
                for (int u = tid; u < 2*BT*3; u += 256) f[u] = 0.f;
            }
            curbi = bi; curbase = base;
#pragma unroll
            for (int t = 0; t < 16; ++t)
                crow[t] = classes[bi * BT + wm * 64 + (t >> 2) * 16 + l4 * 4 + (t & 3)];
        }
        const int row0 = bi * BT, c0 = bj * BT;
        cbi[tl] = bi; cc0[tl] = c0; cval[tl] = (bj > bi);

        f32x4 acc[4][4];
#pragma unroll
        for (int a = 0; a < 4; ++a)
#pragma unroll
            for (int b = 0; b < 4; ++b) acc[a][b] = (f32x4){0.f, 0.f, 0.f, 0.f};

        __syncthreads();                       // prior tile readers + epilogue done
        if (tid < BT) clsc[tid] = classes[c0 + tid];
        const size_t gA = (size_t)(row0 + r0) * D + srcslot * 8;
        const size_t gB = (size_t)(c0   + r0) * D + srcslot * 8;

        for (int kk = 0; kk < KST; ++kk) {
            if (kk) __syncthreads();           // readers done with buffer
#pragma unroll
            for (int pp = 0; pp < 4; ++pp) {
                gload_lds16(normed + gA + (size_t)pp * 32 * D + kk * 64,
                            (ushort*)(sbuf + pp * 4096 + w * 1024));
                gload_lds16(normed + gB + (size_t)pp * 32 * D + kk * 64,
                            (ushort*)(sbuf + 16384 + pp * 4096 + w * 1024));
            }
            __syncthreads();                   // compiler drains vmcnt here
#pragma unroll
            for (int ks = 0; ks < 2; ++ks) {
                bf16x8 af[4], bfr[4];
#pragma unroll
                for (int mf = 0; mf < 4; ++mf) {
                    int ra = wm * 64 + mf * 16 + l15;
                    af[mf] = *(const bf16x8*)(sbuf + ra * 128 +
                              (((ks * 4 + l4) ^ ((ra >> 1) & 7)) << 4));
                }
#pragma unroll
                for (int nf = 0; nf < 4; ++nf) {
                    int rb = wn * 64 + nf * 16 + l15;
                    bfr[nf] = *(const bf16x8*)(sbuf + 16384 + rb * 128 +
                              (((ks * 4 + l4) ^ ((rb >> 1) & 7)) << 4));
                }
#pragma unroll
                for (int mf = 0; mf < 4; ++mf)
#pragma unroll
                    for (int nf = 0; nf < 4; ++nf)
                        acc[mf][nf] = __builtin_amdgcn_mfma_f32_16x16x32_bf16(
                            af[mf], bfr[nf], acc[mf][nf], 0, 0, 0);
            }
        }

        // ---- per-tile epilogue: LDS only (no global stores!) ----
        float cq[4][3];
#pragma unroll
        for (int nf = 0; nf < 4; ++nf) cq[nf][0] = cq[nf][1] = cq[nf][2] = 0.f;
#pragma unroll
        for (int mf = 0; mf < 4; ++mf) {
#pragma unroll
            for (int r = 0; r < 4; ++r) {
                const int rr = wm * 64 + mf * 16 + l4 * 4 + r;
                const int rg = row0 + rr;
                const int cr = crow[mf * 4 + r];
                float z = 0.f, ns = 0.f, p1 = 0.f;
#pragma unroll
                for (int nf = 0; nf < 4; ++nf) {
                    const int cc = wn * 64 + nf * 16 + l15;
                    float t = fmaf(acc[mf][nf][r], TAUINV, -SHIFT);
                    float e = __expf(t);
                    bool same = (cr == clsc[cc]);
                    bool dg   = (rg == c0 + cc);
                    if (!same) { z += e; cq[nf][0] += e; }
                    else if (!dg) { ns += t; p1 += e; cq[nf][1] += t; cq[nf][2] += e; }
                }
#pragma unroll
                for (int m = 1; m < 16; m <<= 1) {
                    z  += __shfl_xor(z,  m, 16);
                    ns += __shfl_xor(ns, m, 16);
                    p1 += __shfl_xor(p1, m, 16);
                }
                if (l15 == 0) {
                    redr[wn][rr][0] += z;
                    redr[wn][rr][1] += ns;
                    redr[wn][rr][2] += p1;
                }
            }
        }
        if (cval[tl]) {                        // col partials -> LDS buffer
#pragma unroll
            for (int nf = 0; nf < 4; ++nf) {
                float a0 = cq[nf][0], a1 = cq[nf][1], a2 = cq[nf][2];
                a0 += __shfl_xor(a0, 16, 64); a0 += __shfl_xor(a0, 32, 64);
                a1 += __shfl_xor(a1, 16, 64); a1 += __shfl_xor(a1, 32, 64);
                a2 += __shfl_xor(a2, 16, 64); a2 += __shfl_xor(a2, 32, 64);
                if (l4 == 0) {
                    int cc = wn * 64 + nf * 16 + l15;
                    redc[wm][tl][cc][0] = a0;
                    redc[wm][tl][cc][1] = a1;
                    redc[wm][tl][cc][2] = a2;
                }
            }
        }
    }

    // ---- block-end flushes (all global stores live here) ----
    __syncthreads();
    if (tid < BT) {                            // final row flush
        int slot = orig - (curbase >> 1);
        size_t o = (size_t)slot * n + curbi * BT + tid;
        Rrow[o]          = redr[0][tid][0] + redr[1][tid][0];
        Rrow[QR + o]     = redr[0][tid][1] + redr[1][tid][1];
        Rrow[2 * QR + o] = redr[0][tid][2] + redr[1][tid][2];
    }
#pragma unroll
    for (int tl = 0; tl < 2; ++tl) {
        if (cval[tl]) {                        // col flush, wm-reduced
            for (int u = tid; u < 384; u += 256) {     // 3 q x 128 cc
                int q = u >> 7, cc = u & 127;
                Rcol[q * QC + (size_t)cbi[tl] * n + cc0[tl] + cc] =
                    redc[0][tl][cc][q] + redc[1][tl][cc][q];
            }
        }
    }
}

// ---------------- K3: per-row closed-form terms ----------------
__global__ void k_rowterms(const float* __restrict__ Rrow,
                           const float* __restrict__ Rcol,
                           const int* __restrict__ classes,
                           const int* __restrict__ hist,
                           float* __restrict__ rowloss,
                           float* __restrict__ rowcnt, int n) {
    int i = blockIdx.x * 256 + threadIdx.x;
    if (i >= n) return;
    const int b_i = i >> 7;
    const size_t QR = (size_t)33 * n;
    const size_t QC = (size_t)64 * n;
    int base = 64 * b_i - (b_i * (b_i - 1)) / 2;
    int firstblk = base >> 1;
    int lastblk  = (base + (64 - b_i) - 1) >> 1;
    int nslots = lastblk - firstblk + 1;
    float z = 0.f, ns = 0.f, p1 = 0.f;
    for (int s = 0; s < nslots; ++s) {
        size_t o = (size_t)s * n + i;
        z += Rrow[o]; ns += Rrow[QR + o]; p1 += Rrow[2 * QR + o];
    }
    for (int b = 0; b < b_i; ++b) {
        size_t o = (size_t)b * n + i;
        z += Rcol[o]; ns += Rcol[QC + o]; p1 += Rcol[2 * QC + o];
    }
    float c = (float)(hist[classes[i] & 127] - 1);
    rowloss[i] = -ns + c * logf(z) + p1 / z;
    rowcnt[i]  = c;
}

// ---------------- K4: final deterministic reduction ----------------
__global__ void k_final(const float* __restrict__ rowloss,
                        const float* __restrict__ rowcnt,
                        float* __restrict__ out, int n) {
    __shared__ float sl[1024];
    __shared__ float sc[1024];
    float l = 0.f, c = 0.f;
    for (int i = threadIdx.x; i < n; i += 1024) {
        l += rowloss[i];
        c += rowcnt[i];
    }
    sl[threadIdx.x] = l;
    sc[threadIdx.x] = c;
    __syncthreads();
    for (int s = 512; s > 0; s >>= 1) {
        if (threadIdx.x < s) {
            sl[threadIdx.x] += sl[threadIdx.x + s];
            sc[threadIdx.x] += sc[threadIdx.x + s];
        }
        __syncthreads();
    }
    if (threadIdx.x == 0)
        out[0] = (sc[0] > 0.f) ? sl[0] / sc[0] : 0.f;
}

extern "C" void kernel_launch(void* const* d_in, const int* in_sizes, int n_in,
                              void* d_out, int out_size, void* d_ws, size_t ws_size,
                              hipStream_t stream) {
    const float* emb     = (const float*)d_in[0];
    const int*   classes = (const int*)d_in[1];
    float*       out     = (float*)d_out;
    const int n = in_sizes[1];                 // 8192
    const int nblk = 1040;                     // 2080 upper-tri tiles / 2

    ushort* normed  = (ushort*)d_ws;                                   // 8 MB
    float*  Rrow    = (float*)((char*)d_ws + (size_t)n * D * 2);       // 3.25 MB
    float*  Rcol    = Rrow + (size_t)3 * 33 * n;                       // 6.29 MB
    float*  rowloss = Rcol + (size_t)3 * 64 * n;
    float*  rowcnt  = rowloss + n;
    int*    hist    = (int*)(rowcnt + n);                              // 512 B

    k_normalize<<<n / 4, 256, 0, stream>>>(emb, classes, normed, hist, n);
    k_zgemm<<<nblk, 256, 0, stream>>>(normed, classes, Rrow, Rcol, n);
    k_rowterms<<<(n + 255) / 256, 256, 0, stream>>>(Rrow, Rcol, classes, hist, rowloss, rowcnt, n);
    k_final<<<1, 1024, 0, stream>>>(rowloss, rowcnt, out, n);
}

// Round 9
// 87.068 us; speedup vs baseline: 2.5708x; 1.3854x over previous
//
#include <hip/hip_runtime.h>
#include <hip/hip_bf16.h>
#include <hip/hip_fp8.h>

// InfoNCE loss, N=8192 D=512 C=128.
// Fixed-shift softmax (M=10): t_ij = s_ij/tau - 10 in [-20, 0].
//   Z_i  = sum_{class!=} e^{t_ij}
//   term = -t_p + log(Z + e^{t_p}) ~= -t_p + logZ + e^{t_p}/Z
// Round 8 -> 9: r5 structure (best measured: ring-3 pipeline, counted
// vmcnt(4), supertile walk, setprio) ported to FP8 e4m3. LDS traffic was the
// dominant pipe (48 KB/block-unit vs ~310cy MFMA); fp8 halves all staging
// and fragment bytes, and the whole 4 MB normed matrix becomes L2-resident.
// BK=64 BYTES per unit -> r5's byte-level addressing carries over verbatim.
// Reads are ds_read_b64, slot swizzle (ks*4+l4)^(((r>>1)&3)<<1) = uniform
// 4 lanes/bank-pair (b64 bandwidth floor). No global stores inside the
// counted-vmcnt loop (r7 lesson).

constexpr int   D      = 512;
constexpr int   BT     = 128;
constexpr int   BK     = 64;         // bytes (fp8 elems) per unit
constexpr int   NSTEP  = D / BK;     // 8
constexpr float TAUINV = 10.0f;
constexpr float SHIFT  = 10.0f;

typedef __attribute__((ext_vector_type(4))) float f32x4;
typedef unsigned char uchar;
typedef unsigned long ulong_t;

__device__ inline uchar f2fp8(float x) {
    __hip_fp8_e4m3 h(x);             // OCP e4m3fn, RNE+sat via HW cvt
    return (uchar)h.__x;
}

__device__ inline void gload_lds16(const uchar* g, void* l) {
    __builtin_amdgcn_global_load_lds(
        (const __attribute__((address_space(1))) void*)g,
        (__attribute__((address_space(3))) void*)l, 16, 0, 0);
}

// ---------------- K1: L2-normalize rows, f32 -> fp8 (+hist in block 0) ----
__global__ void k_normalize(const float* __restrict__ emb,
                            const int* __restrict__ classes,
                            uchar* __restrict__ normed,
                            int* __restrict__ hist, int n) {
    if (blockIdx.x == 0) {
        __shared__ int h[128];
        if (threadIdx.x < 128) h[threadIdx.x] = 0;
        __syncthreads();
        for (int i = threadIdx.x; i < n; i += 256)
            atomicAdd(&h[classes[i] & 127], 1);
        __syncthreads();
        if (threadIdx.x < 128) hist[threadIdx.x] = h[threadIdx.x];
    }
    int row  = blockIdx.x * 4 + (threadIdx.x >> 6);
    int lane = threadIdx.x & 63;
    if (row >= n) return;
    const float4* src = (const float4*)(emb + (size_t)row * D);
    float4 a = src[lane * 2];
    float4 b = src[lane * 2 + 1];
    float ss = a.x*a.x + a.y*a.y + a.z*a.z + a.w*a.w
             + b.x*b.x + b.y*b.y + b.z*b.z + b.w*b.w;
#pragma unroll
    for (int m = 1; m < 64; m <<= 1) ss += __shfl_xor(ss, m, 64);
    float sc = 1.0f / fmaxf(sqrtf(ss), 1e-12f);
    union { uchar c[8]; ulong_t u; } o;
    o.c[0] = f2fp8(a.x * sc); o.c[1] = f2fp8(a.y * sc);
    o.c[2] = f2fp8(a.z * sc); o.c[3] = f2fp8(a.w * sc);
    o.c[4] = f2fp8(b.x * sc); o.c[5] = f2fp8(b.y * sc);
    o.c[6] = f2fp8(b.z * sc); o.c[7] = f2fp8(b.w * sc);
    *(ulong_t*)&normed[(size_t)row * D + lane * 8] = o.u;
}

// ---------------- K2: symmetric masked-exp fp8 GEMM, ring-3 pipeline -------
// Zpart: plane q in 0..2 (Z,NS,P1), each [64 slots][n rows].
__global__ __launch_bounds__(256, 3) void k_zgemm(
    const uchar* __restrict__ normed, const int* __restrict__ classes,
    float* __restrict__ Zpart, int n, int nb, int npairs) {
    __shared__ char ring[3][16384];           // 3 units x (A 8KB | B 8KB)
    __shared__ int clsrow[BT], clscol[BT];

    const int tid  = threadIdx.x;
    const int lane = tid & 63;
    const int w    = tid >> 6;
    const int wm   = w >> 1, wn = w & 1;
    const int l15  = lane & 15, l4 = lane >> 4;
    const size_t QS = (size_t)64 * n;

    // XCD-chunked bijective swizzle
    int q8 = npairs >> 3, r8 = npairs & 7;
    int xcd = blockIdx.x & 7, off = blockIdx.x >> 3;
    int orig = (xcd < r8 ? xcd * (q8 + 1) : r8 * (q8 + 1) + (xcd - r8) * q8) + off;

    // orig -> (bi,bj) via 8x8 supertile walk (2D locality within an XCD)
    const int sgrid = nb >> 3;               // 8
    int idx = orig, si = 0;
    for (;;) { int rc = 36 + (sgrid - 1 - si) * 64; if (idx < rc) break; idx -= rc; ++si; }
    int bi, bj;
    if (idx < 36) { int u = 0, rem = 8; while (idx >= rem) { idx -= rem; ++u; --rem; }
                    bi = si * 8 + u; bj = si * 8 + u + idx; }
    else { idx -= 36; int sj = si + 1 + (idx >> 6); int v = idx & 63;
           bi = si * 8 + (v >> 3); bj = sj * 8 + (v & 7); }
    const int row0 = bi * BT, c0 = bj * BT;
    const bool diagblk = (bi == bj);

    if (tid < BT) clsrow[tid] = classes[row0 + tid];
    else          clscol[tid - BT] = classes[c0 + tid - BT];
    int crow[16];
#pragma unroll
    for (int t = 0; t < 16; ++t)
        crow[t] = classes[row0 + wm * 64 + (t >> 2) * 16 + l4 * 4 + (t & 3)];

    // staging: chunk = 16 rows x 64B (1KB). wave w owns chunks {2w,2w+1}.
    // lane l: row = chunk*16 + (l>>2); LDS dst = base + lane*16 (linear).
    // 16B source slot pre-swizzled: src16 = (l&3) ^ ((l>>3)&3) (involution).
    const int lrow  = lane >> 2;
    const int src16 = (lane & 3) ^ ((lane >> 3) & 3);
    size_t gA[2], gB[2]; int lo[2];
#pragma unroll
    for (int it = 0; it < 2; ++it) {
        int chunk = w * 2 + it;
        int row   = chunk * 16 + lrow;
        gA[it] = (size_t)(row0 + row) * D + src16 * 16;
        gB[it] = (size_t)(c0   + row) * D + src16 * 16;
        lo[it] = chunk * 1024;
    }
    char* ringb = &ring[0][0];

    auto STAGE = [&](int sbo, int kk) {       // kk = unit * 64 (bytes)
#pragma unroll
        for (int it = 0; it < 2; ++it) {
            gload_lds16(normed + gA[it] + kk, ringb + sbo + lo[it]);
            gload_lds16(normed + gB[it] + kk, ringb + sbo + 8192 + lo[it]);
        }
    };

    f32x4 acc[4][4];
#pragma unroll
    for (int a = 0; a < 4; ++a)
#pragma unroll
        for (int b = 0; b < 4; ++b) acc[a][b] = (f32x4){0.f, 0.f, 0.f, 0.f};

    STAGE(0, 0);
    STAGE(16384, BK);
    __builtin_amdgcn_sched_barrier(0);
    asm volatile("s_waitcnt vmcnt(4) lgkmcnt(0)" ::: "memory");
    __builtin_amdgcn_s_barrier();
    __builtin_amdgcn_sched_barrier(0);

    // read swizzle: 8B slot = (ks*4+l4) ^ (((r>>1)&3)<<1); r>>1 mod 4 = l15>>1
    const int rsw = ((l15 >> 1) & 3) << 1;

#pragma unroll
    for (int kt = 0; kt < NSTEP; ++kt) {
        const int cur = kt % 3;
        if (kt + 2 < NSTEP) STAGE(((kt + 2) % 3) * 16384, (kt + 2) * BK);
        const char* la = ringb + cur * 16384;
        const char* lb = la + 8192;
        long af[4][2], bfr[4][2];
#pragma unroll
        for (int mf = 0; mf < 4; ++mf) {
            int ra = wm * 64 + mf * 16 + l15;
#pragma unroll
            for (int ks = 0; ks < 2; ++ks)
                af[mf][ks] = *(const long*)(la + ra * 64 +
                              (((ks * 4 + l4) ^ rsw) << 3));
        }
#pragma unroll
        for (int nf = 0; nf < 4; ++nf) {
            int rb = wn * 64 + nf * 16 + l15;
#pragma unroll
            for (int ks = 0; ks < 2; ++ks)
                bfr[nf][ks] = *(const long*)(lb + rb * 64 +
                              (((ks * 4 + l4) ^ rsw) << 3));
        }
        __builtin_amdgcn_s_setprio(1);
#pragma unroll
        for (int mf = 0; mf < 4; ++mf)
#pragma unroll
            for (int nf = 0; nf < 4; ++nf)
#pragma unroll
                for (int ks = 0; ks < 2; ++ks)
                    acc[mf][nf] = __builtin_amdgcn_mfma_f32_16x16x32_fp8_fp8(
                        af[mf][ks], bfr[nf][ks], acc[mf][nf], 0, 0, 0);
        __builtin_amdgcn_s_setprio(0);
        __builtin_amdgcn_sched_barrier(0);
        if (kt + 2 < NSTEP)       asm volatile("s_waitcnt vmcnt(4)" ::: "memory");
        else if (kt + 2 == NSTEP) asm volatile("s_waitcnt vmcnt(0)" ::: "memory");
        if (kt + 1 < NSTEP) {
            __builtin_amdgcn_s_barrier();
            __builtin_amdgcn_sched_barrier(0);
        }
    }
    __syncthreads();   // full drain before LDS overlay

    // ---- epilogue: masked accumulation of (Z, NS, P1) ----
    float cqz[4] = {0,0,0,0}, cqn[4] = {0,0,0,0}, cqp[4] = {0,0,0,0};
    float* redr = (float*)ringb;              // [2(wn)][128][3]
    float* redc = (float*)(ringb + 16384);    // [2(wm)][128][3]

#pragma unroll
    for (int mf = 0; mf < 4; ++mf) {
#pragma unroll
        for (int r = 0; r < 4; ++r) {
            int rr = wm * 64 + mf * 16 + l4 * 4 + r;
            int rg = row0 + rr;
            int cr = crow[mf * 4 + r];
            float z = 0.f, ns = 0.f, p1 = 0.f;
#pragma unroll
            for (int nf = 0; nf < 4; ++nf) {
                int cc = wn * 64 + nf * 16 + l15;
                float t = fmaf(acc[mf][nf][r], TAUINV, -SHIFT);
                float e = __expf(t);
                bool same = (cr == clscol[cc]);
                bool dg   = (rg == c0 + cc);
                if (!same) { z += e; cqz[nf] += e; }
                else if (!dg) { ns += t; p1 += e; cqn[nf] += t; cqp[nf] += e; }
            }
#pragma unroll
            for (int m = 1; m < 16; m <<= 1) {
                z  += __shfl_xor(z,  m, 16);
                ns += __shfl_xor(ns, m, 16);
                p1 += __shfl_xor(p1, m, 16);
            }
            if (l15 == 0) {
                float* p = &redr[(wn * 128 + rr) * 3];
                p[0] = z; p[1] = ns; p[2] = p1;
            }
        }
    }
    if (!diagblk) {
#pragma unroll
        for (int nf = 0; nf < 4; ++nf) {
            float z = cqz[nf], nsv = cqn[nf], p = cqp[nf];
            z += __shfl_xor(z, 16, 64);  z += __shfl_xor(z, 32, 64);
            nsv += __shfl_xor(nsv, 16, 64); nsv += __shfl_xor(nsv, 32, 64);
            p += __shfl_xor(p, 16, 64);  p += __shfl_xor(p, 32, 64);
            if (l4 == 0) {
                float* pp = &redc[(wm * 128 + wn * 64 + nf * 16 + l15) * 3];
                pp[0] = z; pp[1] = nsv; pp[2] = p;
            }
        }
    }
    __syncthreads();

    if (tid < BT) {                           // row-side partials, slot = bj
#pragma unroll
        for (int q = 0; q < 3; ++q)
            Zpart[q * QS + (size_t)bj * n + row0 + tid] =
                redr[(0 * 128 + tid) * 3 + q] + redr[(1 * 128 + tid) * 3 + q];
    } else if (!diagblk) {                    // col-side partials, slot = bi
        int cc = tid - BT;
#pragma unroll
        for (int q = 0; q < 3; ++q)
            Zpart[q * QS + (size_t)bi * n + c0 + cc] =
                redc[(0 * 128 + cc) * 3 + q] + redc[(1 * 128 + cc) * 3 + q];
    }
}

// ---------------- K3: per-row closed-form terms ----------------
__global__ void k_rowterms(const float* __restrict__ Zpart,
                           const int* __restrict__ classes,
                           const int* __restrict__ hist,
                           float* __restrict__ rowloss,
                           float* __restrict__ rowcnt, int n) {
    int i = blockIdx.x * 256 + threadIdx.x;
    if (i >= n) return;
    const size_t QS = (size_t)64 * n;
    float z = 0.f, ns = 0.f, p1 = 0.f;
    for (int s = 0; s < 64; ++s) {
        size_t o = (size_t)s * n + i;
        z  += Zpart[o];
        ns += Zpart[QS + o];
        p1 += Zpart[2 * QS + o];
    }
    float c = (float)(hist[classes[i] & 127] - 1);
    rowloss[i] = -ns + c * logf(z) + p1 / z;
    rowcnt[i]  = c;
}

// ---------------- K4: final deterministic reduction ----------------
__global__ void k_final(const float* __restrict__ rowloss,
                        const float* __restrict__ rowcnt,
                        float* __restrict__ out, int n) {
    __shared__ float sl[1024];
    __shared__ float sc[1024];
    float l = 0.f, c = 0.f;
    for (int i = threadIdx.x; i < n; i += 1024) {
        l += rowloss[i];
        c += rowcnt[i];
    }
    sl[threadIdx.x] = l;
    sc[threadIdx.x] = c;
    __syncthreads();
    for (int s = 512; s > 0; s >>= 1) {
        if (threadIdx.x < s) {
            sl[threadIdx.x] += sl[threadIdx.x + s];
            sc[threadIdx.x] += sc[threadIdx.x + s];
        }
        __syncthreads();
    }
    if (threadIdx.x == 0)
        out[0] = (sc[0] > 0.f) ? sl[0] / sc[0] : 0.f;
}

extern "C" void kernel_launch(void* const* d_in, const int* in_sizes, int n_in,
                              void* d_out, int out_size, void* d_ws, size_t ws_size,
                              hipStream_t stream) {
    const float* emb     = (const float*)d_in[0];
    const int*   classes = (const int*)d_in[1];
    float*       out     = (float*)d_out;
    const int n  = in_sizes[1];               // 8192
    const int nb = n / BT;                    // 64
    const int npairs = nb * (nb + 1) / 2;     // 2080

    uchar*  normed  = (uchar*)d_ws;                                    // 4 MB
    float*  Zpart   = (float*)((char*)d_ws + (size_t)n * D);           // 6 MB
    float*  rowloss = Zpart + (size_t)3 * 64 * n;
    float*  rowcnt  = rowloss + n;
    int*    hist    = (int*)(rowcnt + n);                              // 512 B

    k_normalize<<<n / 4, 256, 0, stream>>>(emb, classes, normed, hist, n);
    k_zgemm<<<npairs, 256, 0, stream>>>(normed, classes, Zpart, n, nb, npairs);
    k_rowterms<<<(n + 255) / 256, 256, 0, stream>>>(Zpart, classes, hist, rowloss, rowcnt, n);
    k_final<<<1, 1024, 0, stream>>>(rowloss, rowcnt, out, n);
}

// Round 10
// 81.820 us; speedup vs baseline: 2.7357x; 1.0641x over previous
//
#include <hip/hip_runtime.h>
#include <hip/hip_bf16.h>
#include <hip/hip_fp8.h>

// InfoNCE loss, N=8192 D=512 C=128.
// Fixed-shift softmax (M=10): t_ij = s_ij/tau - 10 in [-20, 0].
//   Z_i  = sum_{class!=} e^{t_ij}
//   term = -t_p + log(Z + e^{t_p}) ~= -t_p + logZ + e^{t_p}/Z
// r9 -> r10: kill the 4-way ds_read_b64 bank conflict (4.26M counted) by
// switching to the r5-proven conflict-free ds_read_b128 pattern
// (slot = l4 ^ ((l15>>1)&3) over 16B slots of 64B rows; measured 0 conflicts).
// The fp8 MFMA needs two non-contiguous 8B k-pieces per b128 read, so
// k_normalize pre-interleaves each 64B k-block: chunk c = bytes
// [c*8,+8) ++ [32+c*8,+8)  ->  b128[.x]=ks0 operand, b128[.y]=ks1 operand.
// Everything else = r9 (ring-3, counted vmcnt(4), supertile walk, setprio,
// no global stores inside the counted-vmcnt loop).

constexpr int   D      = 512;
constexpr int   BT     = 128;
constexpr int   BK     = 64;         // bytes (fp8 elems) per unit
constexpr int   NSTEP  = D / BK;     // 8
constexpr float TAUINV = 10.0f;
constexpr float SHIFT  = 10.0f;

typedef __attribute__((ext_vector_type(4))) float f32x4;
typedef __attribute__((ext_vector_type(2))) long i64x2;
typedef unsigned char uchar;
typedef unsigned long ulong_t;

__device__ inline uchar f2fp8(float x) {
    __hip_fp8_e4m3 h(x);             // OCP e4m3fn, RNE+sat via HW cvt
    return (uchar)h.__x;
}

__device__ inline void gload_lds16(const uchar* g, void* l) {
    __builtin_amdgcn_global_load_lds(
        (const __attribute__((address_space(1))) void*)g,
        (__attribute__((address_space(3))) void*)l, 16, 0, 0);
}

// ---------------- K1: L2-normalize rows, f32 -> fp8 (+hist in block 0) ----
// Output layout: per 64B k-block, chunk c (16B) = k[c*8..c*8+8) ++ k[32+c*8..+8).
__global__ void k_normalize(const float* __restrict__ emb,
                            const int* __restrict__ classes,
                            uchar* __restrict__ normed,
                            int* __restrict__ hist, int n) {
    if (blockIdx.x == 0) {
        __shared__ int h[128];
        if (threadIdx.x < 128) h[threadIdx.x] = 0;
        __syncthreads();
        for (int i = threadIdx.x; i < n; i += 256)
            atomicAdd(&h[classes[i] & 127], 1);
        __syncthreads();
        if (threadIdx.x < 128) hist[threadIdx.x] = h[threadIdx.x];
    }
    int row  = blockIdx.x * 4 + (threadIdx.x >> 6);
    int lane = threadIdx.x & 63;
    if (row >= n) return;
    const float4* src = (const float4*)(emb + (size_t)row * D);
    float4 a = src[lane * 2];
    float4 b = src[lane * 2 + 1];
    float ss = a.x*a.x + a.y*a.y + a.z*a.z + a.w*a.w
             + b.x*b.x + b.y*b.y + b.z*b.z + b.w*b.w;
#pragma unroll
    for (int m = 1; m < 64; m <<= 1) ss += __shfl_xor(ss, m, 64);
    float sc = 1.0f / fmaxf(sqrtf(ss), 1e-12f);
    union { uchar c[8]; ulong_t u; } o;
    o.c[0] = f2fp8(a.x * sc); o.c[1] = f2fp8(a.y * sc);
    o.c[2] = f2fp8(a.z * sc); o.c[3] = f2fp8(a.w * sc);
    o.c[4] = f2fp8(b.x * sc); o.c[5] = f2fp8(b.y * sc);
    o.c[6] = f2fp8(b.z * sc); o.c[7] = f2fp8(b.w * sc);
    // lane's 8 elems = k [lane*8, +8): kblk = lane>>3, j8 = lane&7.
    // j8<4 -> chunk j8, half 0 ; j8>=4 -> chunk j8-4, half 1.
    int j8   = lane & 7;
    int doff = (lane >> 3) * 64 + (j8 & 3) * 16 + (j8 >> 2) * 8;
    *(ulong_t*)&normed[(size_t)row * D + doff] = o.u;
}

// ---------------- K2: symmetric masked-exp fp8 GEMM, ring-3 pipeline -------
// Zpart: plane q in 0..2 (Z,NS,P1), each [64 slots][n rows].
__global__ __launch_bounds__(256, 3) void k_zgemm(
    const uchar* __restrict__ normed, const int* __restrict__ classes,
    float* __restrict__ Zpart, int n, int nb, int npairs) {
    __shared__ char ring[3][16384];           // 3 units x (A 8KB | B 8KB)
    __shared__ int clsrow[BT], clscol[BT];

    const int tid  = threadIdx.x;
    const int lane = tid & 63;
    const int w    = tid >> 6;
    const int wm   = w >> 1, wn = w & 1;
    const int l15  = lane & 15, l4 = lane >> 4;
    const size_t QS = (size_t)64 * n;

    // XCD-chunked bijective swizzle
    int q8 = npairs >> 3, r8 = npairs & 7;
    int xcd = blockIdx.x & 7, off = blockIdx.x >> 3;
    int orig = (xcd < r8 ? xcd * (q8 + 1) : r8 * (q8 + 1) + (xcd - r8) * q8) + off;

    // orig -> (bi,bj) via 8x8 supertile walk (2D locality within an XCD)
    const int sgrid = nb >> 3;               // 8
    int idx = orig, si = 0;
    for (;;) { int rc = 36 + (sgrid - 1 - si) * 64; if (idx < rc) break; idx -= rc; ++si; }
    int bi, bj;
    if (idx < 36) { int u = 0, rem = 8; while (idx >= rem) { idx -= rem; ++u; --rem; }
                    bi = si * 8 + u; bj = si * 8 + u + idx; }
    else { idx -= 36; int sj = si + 1 + (idx >> 6); int v = idx & 63;
           bi = si * 8 + (v >> 3); bj = sj * 8 + (v & 7); }
    const int row0 = bi * BT, c0 = bj * BT;
    const bool diagblk = (bi == bj);

    if (tid < BT) clsrow[tid] = classes[row0 + tid];
    else          clscol[tid - BT] = classes[c0 + tid - BT];
    int crow[16];
#pragma unroll
    for (int t = 0; t < 16; ++t)
        crow[t] = classes[row0 + wm * 64 + (t >> 2) * 16 + l4 * 4 + (t & 3)];

    // staging: chunk = 16 rows x 64B (1KB). wave w owns chunks {2w,2w+1}.
    // lane l: row = chunk*16 + (l>>2); LDS dst = base + lane*16 (linear).
    // 16B source slot pre-swizzled: src16 = (l&3) ^ ((l>>3)&3) (involution).
    const int src16 = (lane & 3) ^ ((lane >> 3) & 3);
    size_t gA[2], gB[2]; int lo[2];
#pragma unroll
    for (int it = 0; it < 2; ++it) {
        int chunk = w * 2 + it;
        int row   = chunk * 16 + (lane >> 2);
        gA[it] = (size_t)(row0 + row) * D + src16 * 16;
        gB[it] = (size_t)(c0   + row) * D + src16 * 16;
        lo[it] = chunk * 1024;
    }
    char* ringb = &ring[0][0];

    auto STAGE = [&](int sbo, int kk) {       // kk = unit * 64 (bytes)
#pragma unroll
        for (int it = 0; it < 2; ++it) {
            gload_lds16(normed + gA[it] + kk, ringb + sbo + lo[it]);
            gload_lds16(normed + gB[it] + kk, ringb + sbo + 8192 + lo[it]);
        }
    };

    f32x4 acc[4][4];
#pragma unroll
    for (int a = 0; a < 4; ++a)
#pragma unroll
        for (int b = 0; b < 4; ++b) acc[a][b] = (f32x4){0.f, 0.f, 0.f, 0.f};

    STAGE(0, 0);
    STAGE(16384, BK);
    __builtin_amdgcn_sched_barrier(0);
    asm volatile("s_waitcnt vmcnt(4) lgkmcnt(0)" ::: "memory");
    __builtin_amdgcn_s_barrier();
    __builtin_amdgcn_sched_barrier(0);

    // b128 read: 16B slot = l4 ^ ((l15>>1)&3)  (r5 pattern, 0 conflicts)
    const int rsw = (l15 >> 1) & 3;

#pragma unroll
    for (int kt = 0; kt < NSTEP; ++kt) {
        const int cur = kt % 3;
        if (kt + 2 < NSTEP) STAGE(((kt + 2) % 3) * 16384, (kt + 2) * BK);
        const char* la = ringb + cur * 16384;
        const char* lb = la + 8192;
        i64x2 af[4], bfr[4];
#pragma unroll
        for (int mf = 0; mf < 4; ++mf) {
            int ra = wm * 64 + mf * 16 + l15;
            af[mf] = *(const i64x2*)(la + ra * 64 + ((l4 ^ rsw) << 4));
        }
#pragma unroll
        for (int nf = 0; nf < 4; ++nf) {
            int rb = wn * 64 + nf * 16 + l15;
            bfr[nf] = *(const i64x2*)(lb + rb * 64 + ((l4 ^ rsw) << 4));
        }
        __builtin_amdgcn_s_setprio(1);
#pragma unroll
        for (int mf = 0; mf < 4; ++mf)
#pragma unroll
            for (int nf = 0; nf < 4; ++nf) {
                acc[mf][nf] = __builtin_amdgcn_mfma_f32_16x16x32_fp8_fp8(
                    af[mf][0], bfr[nf][0], acc[mf][nf], 0, 0, 0);
                acc[mf][nf] = __builtin_amdgcn_mfma_f32_16x16x32_fp8_fp8(
                    af[mf][1], bfr[nf][1], acc[mf][nf], 0, 0, 0);
            }
        __builtin_amdgcn_s_setprio(0);
        __builtin_amdgcn_sched_barrier(0);
        if (kt + 2 < NSTEP)       asm volatile("s_waitcnt vmcnt(4)" ::: "memory");
        else if (kt + 2 == NSTEP) asm volatile("s_waitcnt vmcnt(0)" ::: "memory");
        if (kt + 1 < NSTEP) {
            __builtin_amdgcn_s_barrier();
            __builtin_amdgcn_sched_barrier(0);
        }
    }
    __syncthreads();   // full drain before LDS overlay

    // ---- epilogue: masked accumulation of (Z, NS, P1) ----
    float cqz[4] = {0,0,0,0}, cqn[4] = {0,0,0,0}, cqp[4] = {0,0,0,0};
    float* redr = (float*)ringb;              // [2(wn)][128][3]
    float* redc = (float*)(ringb + 16384);    // [2(wm)][128][3]

#pragma unroll
    for (int mf = 0; mf < 4; ++mf) {
#pragma unroll
        for (int r = 0; r < 4; ++r) {
            int rr = wm * 64 + mf * 16 + l4 * 4 + r;
            int rg = row0 + rr;
            int cr = crow[mf * 4 + r];
            float z = 0.f, ns = 0.f, p1 = 0.f;
#pragma unroll
            for (int nf = 0; nf < 4; ++nf) {
                int cc = wn * 64 + nf * 16 + l15;
                float t = fmaf(acc[mf][nf][r], TAUINV, -SHIFT);
                float e = __expf(t);
                bool same = (cr == clscol[cc]);
                bool dg   = (rg == c0 + cc);
                if (!same) { z += e; cqz[nf] += e; }
                else if (!dg) { ns += t; p1 += e; cqn[nf] += t; cqp[nf] += e; }
            }
#pragma unroll
            for (int m = 1; m < 16; m <<= 1) {
                z  += __shfl_xor(z,  m, 16);
                ns += __shfl_xor(ns, m, 16);
                p1 += __shfl_xor(p1, m, 16);
            }
            if (l15 == 0) {
                float* p = &redr[(wn * 128 + rr) * 3];
                p[0] = z; p[1] = ns; p[2] = p1;
            }
        }
    }
    if (!diagblk) {
#pragma unroll
        for (int nf = 0; nf < 4; ++nf) {
            float z = cqz[nf], nsv = cqn[nf], p = cqp[nf];
            z += __shfl_xor(z, 16, 64);  z += __shfl_xor(z, 32, 64);
            nsv += __shfl_xor(nsv, 16, 64); nsv += __shfl_xor(nsv, 32, 64);
            p += __shfl_xor(p, 16, 64);  p += __shfl_xor(p, 32, 64);
            if (l4 == 0) {
                float* pp = &redc[(wm * 128 + wn * 64 + nf * 16 + l15) * 3];
                pp[0] = z; pp[1] = nsv; pp[2] = p;
            }
        }
    }
    __syncthreads();

    if (tid < BT) {                           // row-side partials, slot = bj
#pragma unroll
        for (int q = 0; q < 3; ++q)
            Zpart[q * QS + (size_t)bj * n + row0 + tid] =
                redr[(0 * 128 + tid) * 3 + q] + redr[(1 * 128 + tid) * 3 + q];
    } else if (!diagblk) {                    // col-side partials, slot = bi
        int cc = tid - BT;
#pragma unroll
        for (int q = 0; q < 3; ++q)
            Zpart[q * QS + (size_t)bi * n + c0 + cc] =
                redc[(0 * 128 + cc) * 3 + q] + redc[(1 * 128 + cc) * 3 + q];
    }
}

// ---------------- K3: per-row closed-form terms ----------------
__global__ void k_rowterms(const float* __restrict__ Zpart,
                           const int* __restrict__ classes,
                           const int* __restrict__ hist,
                           float* __restrict__ rowloss,
                           float* __restrict__ rowcnt, int n) {
    int i = blockIdx.x * 256 + threadIdx.x;
    if (i >= n) return;
    const size_t QS = (size_t)64 * n;
    float z = 0.f, ns = 0.f, p1 = 0.f;
    for (int s = 0; s < 64; ++s) {
        size_t o = (size_t)s * n + i;
        z  += Zpart[o];
        ns += Zpart[QS + o];
        p1 += Zpart[2 * QS + o];
    }
    float c = (float)(hist[classes[i] & 127] - 1);
    rowloss[i] = -ns + c * logf(z) + p1 / z;
    rowcnt[i]  = c;
}

// ---------------- K4: final deterministic reduction ----------------
__global__ void k_final(const float* __restrict__ rowloss,
                        const float* __restrict__ rowcnt,
                        float* __restrict__ out, int n) {
    __shared__ float sl[1024];
    __shared__ float sc[1024];
    float l = 0.f, c = 0.f;
    for (int i = threadIdx.x; i < n; i += 1024) {
        l += rowloss[i];
        c += rowcnt[i];
    }
    sl[threadIdx.x] = l;
    sc[threadIdx.x] = c;
    __syncthreads();
    for (int s = 512; s > 0; s >>= 1) {
        if (threadIdx.x < s) {
            sl[threadIdx.x] += sl[threadIdx.x + s];
            sc[threadIdx.x] += sc[threadIdx.x + s];
        }
        __syncthreads();
    }
    if (threadIdx.x == 0)
        out[0] = (sc[0] > 0.f) ? sl[0] / sc[0] : 0.f;
}

extern "C" void kernel_launch(void* const* d_in, const int* in_sizes, int n_in,
                              void* d_out, int out_size, void* d_ws, size_t ws_size,
                              hipStream_t stream) {
    const float* emb     = (const float*)d_in[0];
    const int*   classes = (const int*)d_in[1];
    float*       out     = (float*)d_out;
    const int n  = in_sizes[1];               // 8192
    const int nb = n / BT;                    // 64
    const int npairs = nb * (nb + 1) / 2;     // 2080

    uchar*  normed  = (uchar*)d_ws;                                    // 4 MB
    float*  Zpart   = (float*)((char*)d_ws + (size_t)n * D);           // 6 MB
    float*  rowloss = Zpart + (size_t)3 * 64 * n;
    float*  rowcnt  = rowloss + n;
    int*    hist    = (int*)(rowcnt + n);                              // 512 B

    k_normalize<<<n / 4, 256, 0, stream>>>(emb, classes, normed, hist, n);
    k_zgemm<<<npairs, 256, 0, stream>>>(normed, classes, Zpart, n, nb, npairs);
    k_rowterms<<<(n + 255) / 256, 256, 0, stream>>>(Zpart, classes, hist, rowloss, rowcnt, n);
    k_final<<<1, 1024, 0, stream>>>(rowloss, rowcnt, out, n);
}